// Round 4
// baseline (416.302 us; speedup 1.0000x reference)
//
#include <hip/hip_runtime.h>
#include <stdint.h>
#include <math.h>

#define BB 256
#define VV 128
#define MM 256
#define TDIM 10
#define HH 1024
#define IN_DIM 35840
#define KSPLIT 16
#define KSLICE 2240   /* IN_DIM/KSPLIT */
#define BK 32
#define NCHUNK 70     /* KSLICE/BK */

using f32x4  = __attribute__((ext_vector_type(4))) float;
using bf16x8 = __attribute__((ext_vector_type(8))) short;

__device__ __forceinline__ unsigned short f2bf(float f) {
    unsigned int u = __float_as_uint(f);
    unsigned int r = (u + 0x7FFFu + ((u >> 16) & 1u)) >> 16;
    return (unsigned short)r;
}

// ---------------- K1: build pred_input in bf16 -------------------------
// 512 threads (8 waves, 2/SIMD). Gather loop: 4-way p-split, 64 iters,
// unroll 8, clamped UNCONDITIONAL loads so 8 loads pipeline per batch.
__global__ __launch_bounds__(512)
void k_build(const float* __restrict__ x, const float* __restrict__ memory,
             const int* __restrict__ timings, const float* __restrict__ msurp,
             const float* __restrict__ lastp, short* __restrict__ A)
{
    int b = blockIdx.x, t = threadIdx.x;
    __shared__ int t_s[MM], idx_s[MM], st_s[MM];
    __shared__ float s_surprise;

    if (t < MM) t_s[t] = (t == 0) ? 0 : timings[b*MM + t - 1] + 1;
    if (t < 64) {
        float v = x[b*VV + t] * lastp[b*VV + t]
                + x[b*VV + t + 64] * lastp[b*VV + t + 64];
        #pragma unroll
        for (int off = 32; off > 0; off >>= 1)
            v += __shfl_down(v, off, 64);
        if (t == 0) s_surprise = -logf(v + 1e-8f);
    }
    __syncthreads();

    if (t < MM) {
        int ti = t_s[t], cnt = 0;
        #pragma unroll 4
        for (int j = 0; j < MM; ++j) {
            int tj = t_s[j];
            cnt += (tj < ti) || (tj == ti && j < t);
        }
        idx_s[cnt] = t;
        st_s[cnt]  = ti;
    }
    __syncthreads();

    short* Ab = A + (size_t)b * IN_DIM;
    if (t < MM) {
        float invm = 1.f / ((float)st_s[MM-1] + 1.f);
        int st = st_s[t], src = idx_s[t];
        #pragma unroll
        for (int tt = 0; tt < TDIM; ++tt)
            Ab[32768 + t*TDIM + tt] = (short)f2bf((float)((st >> tt) & 1));
        Ab[35328 + t] = (short)f2bf((float)st * invm);
        float sv = (src == 0) ? s_surprise : msurp[b*MM + src - 1] * 0.99f;
        Ab[35584 + t] = (short)f2bf(sv);
    }

    // gather memory rows -> A (sorted order). quarter q4 handles p = q4+4i.
    int q4 = t >> 7, v = t & (VV-1);
    float xv = x[b*VV + v];
    #pragma unroll 8
    for (int p = q4; p < MM; p += 4) {
        int src = idx_s[p];
        int row = (src == 0) ? 0 : src - 1;           // clamped, always valid
        float mv = memory[((size_t)b*MM + row)*VV + v];
        float val = (src == 0) ? xv : mv;
        Ab[p*VV + v] = (short)f2bf(val);
    }
}

// ---------------- K2: split-K bf16 MFMA GEMM, A direct-to-register -----
// grid (16, 32): x = k-split ks, y = n-tile xt (xt<16 -> W1, else Wg).
// Blocks sharing an A k-slice are ids ks+16*xt == ks (mod 8) -> same XCD,
// so the 1.15MB A slice is L2-resident: A frags load GLOBAL->VGPR
// directly (no LDS, no barrier dependence), double-buffered 1 chunk ahead.
// W (573KB/block, single-use HBM stream) is the only LDS operand:
// reg-staged (coalesced fp32 loads 2 chunks ahead) -> f2bf -> ds_write
// into a 2-buffer ring; frag reads are 4x ds_read_b128.
// Per chunk: ONE raw s_barrier guarded by lgkmcnt(0) only -- vmcnt is
// never drained in the loop (A/W global loads stay in flight across
// barriers; compiler inserts counted vmcnt waits at first use).
// Wave partition: 8 waves x (32m x 64n): af 2, bfr 4, acc 2x4.
// LDS: 2 x 4KB = 8KB. VGPR ~92 -> 2 blocks/CU.
__global__ __launch_bounds__(512, 4)
void k_gemm(const short* __restrict__ A, const float* __restrict__ W1,
            const float* __restrict__ Wg, float* __restrict__ P)
{
    int ks = blockIdx.x;          // 0..15
    int xt = blockIdx.y;          // 0..31
    const float* W = (xt < 16) ? W1 : Wg;
    int wcol0 = (xt & 15) * 64;
    int pcol0 = xt * 64;
    int k0 = ks * KSLICE;

    __shared__ bf16x8 Ws8[2][256];    // 8 KB

    int t = threadIdx.x;
    int l = t & 63, wv = t >> 6;          // wv 0..7
    int r = l & 15, q = l >> 4;

    // A row base pointers: wave wv owns m-rows [wv*32, wv*32+32).
    // Lane (r,q) reads A[R][k0 + c*32 + q*8 .. +7] as bf16x8 (16B aligned).
    const short* arow[2];
    #pragma unroll
    for (int mt = 0; mt < 2; ++mt) {
        int R = wv*32 + mt*16 + r;
        arow[mt] = A + (size_t)R*IN_DIM + k0 + q*8;
    }

    // W frag slots (chunk-invariant): col-row R, granule q, swz q^((R>>1)&3)
    int boff[4];
    #pragma unroll
    for (int nt = 0; nt < 4; ++nt) {
        int R = nt*16 + r;
        boff[nt] = R*4 + (q ^ ((R >> 1) & 3));
    }

    f32x4 acc[2][4];
    #pragma unroll
    for (int mt = 0; mt < 2; ++mt)
        #pragma unroll
        for (int nt = 0; nt < 4; ++nt)
            acc[mt][nt] = (f32x4){0.f, 0.f, 0.f, 0.f};

    // W staging: thread -> (n = l, k-quad = wv): 4 floats, k = kc + wv*4 + j
    int wn = l;
    int wkg = wv >> 1, whalf = wv & 1;    // granule, 8B half
    int wslot16 = (wn*4 + (wkg ^ ((wn >> 1) & 3))) * 16 + whalf * 8;
    const float* wbase = W + (size_t)(k0 + wv*4)*HH + wcol0 + wn;

#define LOADA(AF, cc) do {                                                    \
        int ko_ = (cc)*BK;                                                    \
        _Pragma("unroll")                                                     \
        for (int mt_ = 0; mt_ < 2; ++mt_)                                     \
            AF[mt_] = *(const bf16x8*)(arow[mt_] + ko_);                      \
    } while (0)

#define WLOAD(wreg, cc) do {                                                  \
        const float* wp_ = wbase + (size_t)(cc)*BK*HH;                        \
        _Pragma("unroll")                                                     \
        for (int j_ = 0; j_ < 4; ++j_) wreg[j_] = wp_[(size_t)j_*HH];         \
    } while (0)

#define WCONV(wreg, wdst) do {                                                \
        unsigned int lo_ = (unsigned int)f2bf(wreg[0])                        \
                         | ((unsigned int)f2bf(wreg[1]) << 16);               \
        unsigned int hi_ = (unsigned int)f2bf(wreg[2])                        \
                         | ((unsigned int)f2bf(wreg[3]) << 16);               \
        unsigned int* d_ = (unsigned int*)((char*)&Ws8[wdst][0] + wslot16);   \
        d_[0] = lo_; d_[1] = hi_;                                             \
    } while (0)

    bf16x8 afA[2], afB[2];
    float wA[4], wB[4], w0[4];

    // ---- prologue ----
    WLOAD(w0, 0);
    LOADA(afA, 0);
    WLOAD(wA, 1);
    WCONV(w0, 0);                         // Ws[0] = W(0)
    asm volatile("s_waitcnt lgkmcnt(0)" ::: "memory");
    __builtin_amdgcn_s_barrier();

    // chunk c: MFMA(AF=A(c), Ws[c&1]); prefetch A(c+1)->AFN, W(c+2)->WNXT;
    // convert WCUR(=W(c+1)) into Ws[(c+1)&1]; lgkm-only barrier.
#define CHUNK(c, AF, AFN, WCUR, WNXT) do {                                    \
        int cA_ = ((c) + 1 < NCHUNK) ? (c) + 1 : NCHUNK - 1;                  \
        int cW_ = ((c) + 2 < NCHUNK) ? (c) + 2 : NCHUNK - 1;                  \
        LOADA(AFN, cA_);                                                      \
        WLOAD(WNXT, cW_);                                                     \
        {                                                                     \
            bf16x8 bf_[4];                                                    \
            _Pragma("unroll")                                                 \
            for (int nt = 0; nt < 4; ++nt) bf_[nt] = Ws8[(c) & 1][boff[nt]];  \
            _Pragma("unroll")                                                 \
            for (int mt = 0; mt < 2; ++mt)                                    \
                _Pragma("unroll")                                             \
                for (int nt = 0; nt < 4; ++nt)                                \
                    acc[mt][nt] = __builtin_amdgcn_mfma_f32_16x16x32_bf16(    \
                        AF[mt], bf_[nt], acc[mt][nt], 0, 0, 0);               \
        }                                                                     \
        WCONV(WCUR, ((c) + 1) & 1);                                           \
        asm volatile("s_waitcnt lgkmcnt(0)" ::: "memory");                    \
        __builtin_amdgcn_s_barrier();                                         \
    } while (0)

    #pragma unroll 1
    for (int c = 0; c < NCHUNK; c += 2) {
        CHUNK(c,     afA, afB, wA, wB);
        CHUNK(c + 1, afB, afA, wB, wA);
    }
#undef CHUNK
#undef WCONV
#undef WLOAD
#undef LOADA

    // epilogue: partials P[ks][m][2048]
    #pragma unroll
    for (int mt = 0; mt < 2; ++mt)
        #pragma unroll
        for (int nt = 0; nt < 4; ++nt)
            #pragma unroll
            for (int rg = 0; rg < 4; ++rg) {
                int m = wv*32 + mt*16 + q*4 + rg;
                int n = pcol0 + nt*16 + r;
                P[((size_t)ks*BB + m)*2048 + n] = acc[mt][nt][rg];
            }
}

// ---------------- K3: fused split-K reduce + gate + (h @ W2 + b2) ------
// 512 threads, one block per batch row. Phase 1: each thread sums one
// f32x4 quad of P over 16 k-splits (16 independent loads in flight).
// Phase 2: gate -> h in LDS. Phase 3: W2 matvec with 4-way k-split.
__global__ __launch_bounds__(512)
void k_tail(const float* __restrict__ P, const float* __restrict__ b1,
            const float* __restrict__ bg, const float* __restrict__ W2,
            const float* __restrict__ b2, float* __restrict__ out)
{
    int b = blockIdx.x, t = threadIdx.x;
    __shared__ f32x4 part[512];          // 8 KB
    __shared__ float hs[HH];             // 4 KB
    __shared__ float s2[512];            // 2 KB

    const f32x4* P4 = (const f32x4*)P;
    f32x4 s = (f32x4){0.f, 0.f, 0.f, 0.f};
    #pragma unroll
    for (int ks = 0; ks < KSPLIT; ++ks)
        s += P4[((size_t)ks*BB + b)*512 + t];
    part[t] = s;
    __syncthreads();

    if (t < 256) {
        f32x4 p1 = part[t]       + ((const f32x4*)b1)[t];
        f32x4 pg = part[t + 256] + ((const f32x4*)bg)[t];
        f32x4 o;
        #pragma unroll
        for (int j = 0; j < 4; ++j)
            o[j] = p1[j] / (1.f + expf(-pg[j]));
        ((f32x4*)hs)[t] = o;
    }
    __syncthreads();

    int v = t & 127, kh = t >> 7;        // 4-way k-split, 256 k each
    const float* wp = W2 + (size_t)kh*256*VV + v;
    const float* hk = hs + kh*256;
    float acc = 0.f;
    #pragma unroll 8
    for (int k = 0; k < 256; ++k)
        acc += hk[k] * wp[(size_t)k*VV];
    s2[t] = acc;
    __syncthreads();
    if (t < 128)
        out[(size_t)b*VV + v] = s2[t] + s2[t+128] + s2[t+256] + s2[t+384] + b2[v];
}

extern "C" void kernel_launch(void* const* d_in, const int* in_sizes, int n_in,
                              void* d_out, int out_size, void* d_ws, size_t ws_size,
                              hipStream_t stream)
{
    const float* x    = (const float*)d_in[0];
    const float* mem  = (const float*)d_in[1];
    const int*   tim  = (const int*)d_in[2];
    const float* msur = (const float*)d_in[3];
    const float* lp   = (const float*)d_in[4];
    const float* W1   = (const float*)d_in[5];
    const float* b1   = (const float*)d_in[6];
    const float* Wg   = (const float*)d_in[7];
    const float* bg   = (const float*)d_in[8];
    const float* W2   = (const float*)d_in[9];
    const float* b2   = (const float*)d_in[10];
    float* out = (float*)d_out;

    // ws layout: A bf16 [256][35840] | P fp32 [16][256][2048]
    short* A = (short*)d_ws;
    float* P = (float*)((char*)d_ws + 18350080);

    k_build <<<256, 512, 0, stream>>>(x, mem, tim, msur, lp, A);
    k_gemm  <<<dim3(KSPLIT, 32), 512, 0, stream>>>(A, W1, Wg, P);
    k_tail  <<<256, 512, 0, stream>>>(P, b1, bg, W2, b2, out);
}